// Round 2
// baseline (1258.388 us; speedup 1.0000x reference)
//
#include <hip/hip_runtime.h>
#include <hip/hip_cooperative_groups.h>
#include <cmath>

// ---------------- problem constants ----------------
#define FEAT  192
#define CINCH 384          // CIN
#define CGATE 768
#define BATCH 16
#define HH    64
#define WW    64
#define NP    (BATCH*HH*WW)   // 65536 flattened (b,y,w)
#define KI2S  768             // 384 ic * 2 live taps
#define KS2S  576             // 192 feat * 3 taps
#define NBLK  96              // scan blocks: 8 slots(2 batches each) x 12 f-chunks

using bf16   = __bf16;
using bf16x8 = __attribute__((ext_vector_type(8))) __bf16;
using bf16x4 = __attribute__((ext_vector_type(4))) __bf16;
using f32x4  = __attribute__((ext_vector_type(4))) float;
typedef unsigned long long u64;

// ---------------------------------------------------------------
// IC-coherent accessors: relaxed agent-scope atomics -> plain
// global_load/store with sc0/sc1 (bypass L1+L2, coherent at Infinity
// Cache). No cache-wide wbl2/inv on the per-row path.
// Visibility rule: store completion (vmcnt==0, provided by the
// __syncthreads drain) => data at IC => any sc1 load sees it.
// ---------------------------------------------------------------
__device__ __forceinline__ void ic_store64(u64* p, u64 v) {
    __hip_atomic_store(p, v, __ATOMIC_RELAXED, __HIP_MEMORY_SCOPE_AGENT);
}
__device__ __forceinline__ u64 ic_load64(const u64* p) {
    return __hip_atomic_load(p, __ATOMIC_RELAXED, __HIP_MEMORY_SCOPE_AGENT);
}

__device__ __forceinline__ float sigm_fast(float v) {
    return __builtin_amdgcn_rcpf(1.f + __expf(-v));
}
__device__ __forceinline__ float tanh_fast(float v) {
    // 1 - 2/(1+e^{2v}); saturates correctly for |v| large
    return 1.f - 2.f * __builtin_amdgcn_rcpf(1.f + __expf(2.f * v));
}

// ============================================================
// Pack weights into bf16 GEMM operand layouts (A row-major, k contiguous).
// ============================================================
__global__ void pack_weights(const float* __restrict__ wi, const float* __restrict__ ws,
                             const float* __restrict__ wk,
                             bf16* __restrict__ WpA, bf16* __restrict__ WpS,
                             bf16* __restrict__ WpK) {
    int tid = blockIdx.x * 256 + threadIdx.x;
    int stride = gridDim.x * 256;
    for (int idx = tid; idx < CGATE * KI2S; idx += stride) {
        int cp = idx / KI2S, k = idx % KI2S;
        int q = cp / 192, r = cp % 192, g = r / 64, f = r % 64;
        int c = g * 256 + q * 64 + f;             // original (pre-shuffle) out channel
        float v;
        if (k < CINCH) {
            v = wi[(c * CINCH + k) * 3 + 0];      // tap0: full
        } else {
            int ic = k - CINCH;                   // tap1: causal group mask
            v = (g >= ic / 128) ? wi[(c * CINCH + ic) * 3 + 1] : 0.f;
        }
        WpA[idx] = (bf16)v;
    }
    for (int idx = tid; idx < CGATE * KS2S; idx += stride) {
        int oc = idx / KS2S, k = idx % KS2S;
        int t = k / FEAT, f = k % FEAT;
        WpS[idx] = (bf16)ws[(oc * FEAT + f) * 3 + t];
    }
    for (int idx = tid; idx < CINCH * FEAT; idx += stride) {
        int co = idx / FEAT, f = idx % FEAT;
        WpK[idx] = (co / 128 >= f / 64) ? (bf16)wk[idx] : (bf16)0.f;
    }
}

// ============================================================
// Pack x (fp32 NCHW) -> Xp bf16 [p=(b,y,w)][k=768]
// ============================================================
__global__ void pack_x(const float* __restrict__ x, bf16* __restrict__ Xp) {
    __shared__ float tile[64][65];
    int b = blockIdx.x >> 6, y = blockIdx.x & 63;
    const float* xb = x + ((size_t)b * CINCH * HH + y) * WW;
    bf16* Xrow = Xp + ((size_t)b * HH * WW + (size_t)y * WW) * KI2S;
    for (int ic0 = 0; ic0 < CINCH; ic0 += 64) {
        for (int rep = 0; rep < 16; ++rep) {
            int idx = rep * 256 + threadIdx.x;
            int i = idx >> 6, w = idx & 63;
            tile[i][w] = xb[(size_t)(ic0 + i) * (HH * WW) + w];
        }
        __syncthreads();
        for (int rep = 0; rep < 16; ++rep) {
            int idx = rep * 256 + threadIdx.x;
            int w = idx >> 6, i = idx & 63;
            Xrow[(size_t)w * KI2S + CINCH + ic0 + i] = (bf16)tile[i][w];
            Xrow[(size_t)w * KI2S + ic0 + i] = (w == 0) ? (bf16)0.f : (bf16)tile[i][w - 1];
        }
        __syncthreads();
    }
}

// ============================================================
// i2s GEMM: Hbuf[c'][p] = sum_k WpA[c'][k] * Xp[p][k]  (unchanged, verified)
// ============================================================
__global__ __launch_bounds__(256) void gemm_i2s(const bf16* __restrict__ A,
                                                const bf16* __restrict__ B,
                                                bf16* __restrict__ Hout) {
    __shared__ __align__(16) bf16 As[128 * 64];
    __shared__ __align__(16) bf16 Bs[128 * 64];
    const int m0 = blockIdx.y * 128;
    const int p0 = blockIdx.x * 128;
    const int tid = threadIdx.x;
    const int lane = tid & 63, wid = tid >> 6;
    const int quad = lane >> 4, col = lane & 15;
    const int mhalf = (wid & 1) * 64, nhalf = (wid >> 1) * 64;
    f32x4 acc[4][4] = {};
    for (int k0 = 0; k0 < KI2S; k0 += 64) {
        for (int r = 0; r < 4; ++r) {
            int L = r * 256 + tid;
            int row = L >> 3, slot = L & 7;
            int c = slot ^ (row & 7);
            ((uint4*)As)[L] = *(const uint4*)(&A[(size_t)(m0 + row) * KI2S + k0 + c * 8]);
            ((uint4*)Bs)[L] = *(const uint4*)(&B[(size_t)(p0 + row) * KI2S + k0 + c * 8]);
        }
        __syncthreads();
        for (int kk = 0; kk < 2; ++kk) {
            bf16x8 af[4], bfv[4];
            for (int mt = 0; mt < 4; ++mt) {
                int row = mhalf + mt * 16 + col;
                int slot = (kk * 4 + quad) ^ (row & 7);
                af[mt] = *(const bf16x8*)(&As[row * 64 + slot * 8]);
            }
            for (int nt = 0; nt < 4; ++nt) {
                int row = nhalf + nt * 16 + col;
                int slot = (kk * 4 + quad) ^ (row & 7);
                bfv[nt] = *(const bf16x8*)(&Bs[row * 64 + slot * 8]);
            }
            for (int mt = 0; mt < 4; ++mt)
                for (int nt = 0; nt < 4; ++nt)
                    acc[mt][nt] = __builtin_amdgcn_mfma_f32_16x16x32_bf16(
                        af[mt], bfv[nt], acc[mt][nt], 0, 0, 0);
        }
        __syncthreads();
    }
    for (int mt = 0; mt < 4; ++mt)
        for (int nt = 0; nt < 4; ++nt) {
            int m = m0 + mhalf + mt * 16 + quad * 4;
            int p = p0 + nhalf + nt * 16 + col;
            for (int r = 0; r < 4; ++r)
                Hout[(size_t)(m + r) * NP + p] = (bf16)acc[mt][nt][r];
        }
}

// ============================================================
// Cooperative row scan, batch-paired: 96 blocks = 8 slots x 12 chunks.
// Each block advances TWO independent batches (2s, 2s+1); batch B's
// compute hides batch A's IC exchange latency and vice versa.
// Arrivals: 12 per batch-row (tid0, after a __syncthreads that has
// already drained the publish stores via its vmcnt(0)).
// ============================================================
__global__ __launch_bounds__(256) void scan_kernel(
    const bf16* __restrict__ Hbuf,   // [768][65536]
    const bf16* __restrict__ Ws2s,   // [768][576]
    const bf16* __restrict__ Wskip,  // [384][192]
    const float* __restrict__ x,
    const float* __restrict__ b_skip,
    float* __restrict__ out,
    bf16* __restrict__ hg,           // [3][16][66*192]
    unsigned* __restrict__ cnt) {    // [16][32] padded counters
    cooperative_groups::grid_group grid = cooperative_groups::this_grid();
    __shared__ __align__(16) bf16 hlds[2][66 * 200];   // staged h rows (halo idx)
    __shared__ __align__(16) bf16 hnew[2][64 * 20];    // own 16f slices of h(y)
    const int bid = blockIdx.x;
    const int s = bid & 7;              // slot (XCD-affine)
    const int j = bid >> 3;             // feature chunk 0..11
    const int b0 = s * 2, b1 = s * 2 + 1;
    const int tid = threadIdx.x, lane = tid & 63, wid = tid >> 6;
    const int quad = lane >> 4, col = lane & 15;

    // ---- init: zero hg + counters + hlds (h(-1)=0 for both batches) ----
    {
        const int total = 3 * 16 * 66 * 192 / 2;   // dwords
        for (int i = bid * 256 + tid; i < total; i += NBLK * 256)
            ((unsigned*)hg)[i] = 0u;
        if (bid < 16 && tid < 32) cnt[bid * 32 + tid] = 0u;
        for (int i = tid; i < 2 * 66 * 100; i += 256) ((unsigned*)hlds)[i] = 0u;
    }
    // persistent A fragments (shared by both batches)
    bf16x8 Ag[18];
    {
        int f = 16 * j + wid * 4 + (col >> 2), q = col & 3;
        const bf16* Arow = Ws2s + (size_t)(q * 192 + f) * KS2S + quad * 8;
        for (int kc = 0; kc < 18; ++kc) Ag[kc] = *(const bf16x8*)(Arow + kc * 32);
    }
    bf16x8 Ak[6];
    const int mtk = wid & 1, ntk0 = (wid >> 1) * 2;
    {
        int co = 32 * j + mtk * 16 + col;
        const bf16* Krow = Wskip + (size_t)co * FEAT + quad * 8;
        for (int kc = 0; kc < 6; ++kc) Ak[kc] = *(const bf16x8*)(Krow + kc * 32);
    }
    const int fmine = 16 * j + wid * 4 + quad;
    const int lf = wid * 4 + quad;              // local feature 0..15
    float cstate[2][4] = {};
    unsigned* cntA = cnt + b0 * 32;
    unsigned* cntB = cnt + b1 * 32;
    grid.sync();   // one-time: init visibility (fences flush zeros to IC)

    float hadd[2][4][4];
    #pragma unroll
    for (int ib = 0; ib < 2; ++ib) {            // gate biases, row 0
        const size_t prow = (size_t)(s * 2 + ib) * HH * WW;
        for (int nt = 0; nt < 4; ++nt) {
            int w = nt * 16 + col;
            for (int r = 0; r < 4; ++r)
                hadd[ib][nt][r] = (float)Hbuf[(size_t)(r * FEAT + fmine) * NP + prow + w];
        }
    }

#define GATES_LSTM(IB) do {                                                        \
    f32x4 acc_[4] = {};                                                            \
    _Pragma("unroll")                                                              \
    for (int kc = 0; kc < 18; ++kc) {                                              \
        int k0 = kc * 32 + quad * 8;                                               \
        int t = k0 / FEAT, f = k0 % FEAT;                                          \
        _Pragma("unroll")                                                          \
        for (int nt = 0; nt < 4; ++nt) {                                           \
            int w = nt * 16 + col;                                                 \
            bf16x8 bfr = *(const bf16x8*)(&hlds[IB][(w + t) * 200 + f]);           \
            acc_[nt] = __builtin_amdgcn_mfma_f32_16x16x32_bf16(Ag[kc], bfr,        \
                                                               acc_[nt], 0, 0, 0);\
        }                                                                          \
    }                                                                              \
    _Pragma("unroll")                                                              \
    for (int nt = 0; nt < 4; ++nt) {                                               \
        float so = acc_[nt][0] + hadd[IB][nt][0];                                  \
        float sf = acc_[nt][1] + hadd[IB][nt][1];                                  \
        float si = acc_[nt][2] + hadd[IB][nt][2];                                  \
        float sg = acc_[nt][3] + hadd[IB][nt][3];                                  \
        float go = sigm_fast(so), gf = sigm_fast(sf);                              \
        float gi = sigm_fast(si), gg = sigm_fast(sg);                              \
        float cc = gf * cstate[IB][nt] + gi * gg;                                  \
        cstate[IB][nt] = cc;                                                       \
        int w = nt * 16 + col;                                                     \
        hnew[IB][w * 20 + lf] = (bf16)(go * tanh_fast(cc));                        \
    }                                                                              \
} while (0)

#define PUBLISH(IB, BB) do {                                                       \
    bf16* dst = hg + ((size_t)(y % 3) * 16 + (BB)) * (66 * 192);                   \
    int w = tid >> 2, fo = (tid & 3) * 4;                                          \
    u64 v = *(const u64*)(&hnew[IB][w * 20 + fo]);                                 \
    ic_store64((u64*)(dst + (size_t)(w + 1) * 192 + 16 * j + fo), v);              \
} while (0)

#define SKIPGEMM(IB, BB, YM) do {                                                  \
    f32x4 acc2_[2] = {};                                                           \
    _Pragma("unroll")                                                              \
    for (int kc = 0; kc < 6; ++kc)                                                 \
        _Pragma("unroll")                                                          \
        for (int i = 0; i < 2; ++i) {                                              \
            int w = (ntk0 + i) * 16 + col;                                         \
            bf16x8 bfr = *(const bf16x8*)(&hlds[IB][(w + 1) * 200 + kc * 32 +      \
                                                    quad * 8]);                    \
            acc2_[i] = __builtin_amdgcn_mfma_f32_16x16x32_bf16(Ak[kc], bfr,        \
                                                               acc2_[i], 0, 0, 0);\
        }                                                                          \
    _Pragma("unroll")                                                              \
    for (int r = 0; r < 4; ++r) {                                                  \
        int co = 32 * j + mtk * 16 + quad * 4 + r;                                 \
        float bs = b_skip[co];                                                     \
        _Pragma("unroll")                                                          \
        for (int i = 0; i < 2; ++i) {                                              \
            int w = (ntk0 + i) * 16 + col;                                         \
            size_t xi = ((size_t)((BB) * CINCH + co) * HH + (YM)) * WW + w;        \
            out[xi] = x[xi] + bs + acc2_[i][r];                                    \
        }                                                                          \
    }                                                                              \
} while (0)

#define STAGE(IB, BB) do {                                                         \
    const u64* src = (const u64*)(hg + ((size_t)(y % 3) * 16 + (BB)) * (66 * 192));\
    _Pragma("unroll")                                                              \
    for (int it = 0; it < 13; ++it) {                                              \
        int c = it * 256 + tid;                                                    \
        if (c < 66 * 48) {                                                         \
            u64 v = ic_load64(src + c);                                            \
            int w = c / 48, fc = c % 48;                                           \
            *(u64*)(&hlds[IB][w * 200 + fc * 4]) = v;                              \
        }                                                                          \
    }                                                                              \
} while (0)

#define PREFETCH(IB, BB) do {                                                      \
    const size_t prow = (size_t)(BB) * HH * WW + (size_t)(y + 1) * WW;             \
    _Pragma("unroll")                                                              \
    for (int nt = 0; nt < 4; ++nt) {                                               \
        int w = nt * 16 + col;                                                     \
        _Pragma("unroll")                                                          \
        for (int r = 0; r < 4; ++r)                                                \
            hadd[IB][nt][r] = (float)Hbuf[(size_t)(r * FEAT + fmine) * NP +        \
                                          prow + w];                               \
    }                                                                              \
} while (0)

    for (int y = 0; y < 64; ++y) {
        const unsigned tgt = 12u * (unsigned)(y + 1);
        // ---- batch A compute ----
        GATES_LSTM(0);
        __syncthreads();                          // S1: hnew0 complete
        PUBLISH(0, b0);                           // A stores in flight...
        // ---- batch B compute (hides A's store flight) ----
        GATES_LSTM(1);
        __syncthreads();                          // S2: hnew1 complete; pub_A drained (vmcnt0)
        if (tid == 0)
            __hip_atomic_fetch_add(cntA, 1u, __ATOMIC_RELAXED, __HIP_MEMORY_SCOPE_AGENT);
        PUBLISH(1, b1);                           // B stores in flight...
        if (y > 0) SKIPGEMM(0, b0, y - 1);        // hides B's store flight
        __syncthreads();                          // S3: pub_B drained; skip0 hlds reads done
        if (tid == 0)
            __hip_atomic_fetch_add(cntB, 1u, __ATOMIC_RELAXED, __HIP_MEMORY_SCOPE_AGENT);
        if (y > 0) SKIPGEMM(1, b1, y - 1);        // hides A's counter propagation
        if (tid == 0) {                           // spin A (usually first-poll hit)
            while (__hip_atomic_load(cntA, __ATOMIC_RELAXED, __HIP_MEMORY_SCOPE_AGENT) < tgt)
                __builtin_amdgcn_s_sleep(1);
        }
        __syncthreads();                          // S4: A ready; skip1 hlds reads done
        if (y < 63) { PREFETCH(0, b0); PREFETCH(1, b1); }   // drained at S6 (~1µs away)
        STAGE(0, b0);                             // hides B's counter propagation
        {                                         // spin B: all threads (no barrier needed)
            while (__hip_atomic_load(cntB, __ATOMIC_RELAXED, __HIP_MEMORY_SCOPE_AGENT) < tgt)
                __builtin_amdgcn_s_sleep(1);
            asm volatile("" ::: "memory");        // keep stage1 loads after the poll
        }
        STAGE(1, b1);
        __syncthreads();                          // S6: stage writes visible to all
    }

    // ---- epilogue: skip GEMM + residual for row 63, both batches ----
    SKIPGEMM(0, b0, 63);
    SKIPGEMM(1, b1, 63);

#undef GATES_LSTM
#undef PUBLISH
#undef SKIPGEMM
#undef STAGE
#undef PREFETCH
}

// ============================================================
extern "C" void kernel_launch(void* const* d_in, const int* in_sizes, int n_in,
                              void* d_out, int out_size, void* d_ws, size_t ws_size,
                              hipStream_t stream) {
    const float* x      = (const float*)d_in[0];
    const float* w_i2s  = (const float*)d_in[1];
    const float* w_s2s  = (const float*)d_in[2];
    const float* w_skip = (const float*)d_in[3];
    const float* b_skip = (const float*)d_in[4];
    float* out = (float*)d_out;

    char* ws = (char*)d_ws;
    const size_t HBUF_B = (size_t)CGATE * NP * 2;        // 100,663,296
    bf16* Hbuf = (bf16*)ws;
    size_t off = HBUF_B;
    bf16* WpA  = (bf16*)(ws + off); off += (size_t)CGATE * KI2S * 2;
    bf16* WpS  = (bf16*)(ws + off); off += (size_t)CGATE * KS2S * 2;
    bf16* WpK  = (bf16*)(ws + off); off += (size_t)CINCH * FEAT * 2;
    bf16* hg   = (bf16*)(ws + off); off += (size_t)3 * 16 * 66 * 192 * 2;
    unsigned* cnt = (unsigned*)(ws + off);               // 16*32 u32 = 2 KB
    bf16* Xp   = (bf16*)d_out;   // im2col scratch in d_out; dead before scan writes out

    pack_weights<<<256, 256, 0, stream>>>(w_i2s, w_s2s, w_skip, WpA, WpS, WpK);
    pack_x<<<BATCH * HH, 256, 0, stream>>>(x, Xp);
    dim3 g3(NP / 128, CGATE / 128);
    gemm_i2s<<<g3, 256, 0, stream>>>(WpA, Xp, Hbuf);

    void* args[] = { (void*)&Hbuf, (void*)&WpS, (void*)&WpK,
                     (void*)&x, (void*)&b_skip, (void*)&out, (void*)&hg, (void*)&cnt };
    hipLaunchCooperativeKernel((const void*)scan_kernel, dim3(NBLK), dim3(256),
                               args, 0, stream);
}

// Round 5
// 771.945 us; speedup vs baseline: 1.6302x; 1.6302x over previous
//
#include <hip/hip_runtime.h>
#include <hip/hip_cooperative_groups.h>
#include <cmath>

// ---------------- problem constants ----------------
#define FEAT  192
#define CINCH 384          // CIN
#define CGATE 768
#define BATCH 16
#define HH    64
#define WW    64
#define NP    (BATCH*HH*WW)   // 65536 flattened (b,y,w)
#define KI2S  768             // 384 ic * 2 live taps
#define KS2S  576             // 192 feat * 3 taps
#define NBLK  192             // scan blocks: 16 batches x 12 f-chunks

using bf16   = __bf16;
using bf16x8 = __attribute__((ext_vector_type(8))) __bf16;
using bf16x4 = __attribute__((ext_vector_type(4))) __bf16;
using f32x4  = __attribute__((ext_vector_type(4))) float;
typedef unsigned long long u64;

// ---------------------------------------------------------------
// IC-coherent accessors: relaxed agent-scope atomics compile to plain
// global_load/store with sc0/sc1 flags (bypass L1+L2, hit Infinity
// Cache = the cross-XCD coherence point). NO buffer_wbl2 / buffer_inv
// cache-wide maintenance ops are emitted (those come from acq/rel
// fences only). Visibility rule used below: sc1 store completion
// (vmcnt==0) => visible at IC => visible to any sc1 load.
// ---------------------------------------------------------------
__device__ __forceinline__ void ic_store64(u64* p, u64 v) {
    __hip_atomic_store(p, v, __ATOMIC_RELAXED, __HIP_MEMORY_SCOPE_AGENT);
}
__device__ __forceinline__ u64 ic_load64(const u64* p) {
    return __hip_atomic_load(p, __ATOMIC_RELAXED, __HIP_MEMORY_SCOPE_AGENT);
}

__device__ __forceinline__ float sigm_fast(float v) {
    return __builtin_amdgcn_rcpf(1.f + __expf(-v));
}
__device__ __forceinline__ float tanh_fast(float v) {
    // 1 - 2/(1+e^{2v}); saturates correctly for |v| large (exp->inf/0)
    return 1.f - 2.f * __builtin_amdgcn_rcpf(1.f + __expf(2.f * v));
}

// ============================================================
// Pack weights into bf16 GEMM operand layouts (A row-major, k contiguous).
// ============================================================
__global__ void pack_weights(const float* __restrict__ wi, const float* __restrict__ ws,
                             const float* __restrict__ wk,
                             bf16* __restrict__ WpA, bf16* __restrict__ WpS,
                             bf16* __restrict__ WpK) {
    int tid = blockIdx.x * 256 + threadIdx.x;
    int stride = gridDim.x * 256;
    for (int idx = tid; idx < CGATE * KI2S; idx += stride) {
        int cp = idx / KI2S, k = idx % KI2S;
        int q = cp / 192, r = cp % 192, g = r / 64, f = r % 64;
        int c = g * 256 + q * 64 + f;             // original (pre-shuffle) out channel
        float v;
        if (k < CINCH) {
            v = wi[(c * CINCH + k) * 3 + 0];      // tap0: full
        } else {
            int ic = k - CINCH;                   // tap1: causal group mask
            v = (g >= ic / 128) ? wi[(c * CINCH + ic) * 3 + 1] : 0.f;
        }
        WpA[idx] = (bf16)v;
    }
    for (int idx = tid; idx < CGATE * KS2S; idx += stride) {
        int oc = idx / KS2S, k = idx % KS2S;
        int t = k / FEAT, f = k % FEAT;
        WpS[idx] = (bf16)ws[(oc * FEAT + f) * 3 + t];
    }
    for (int idx = tid; idx < CINCH * FEAT; idx += stride) {
        int co = idx / FEAT, f = idx % FEAT;
        WpK[idx] = (co / 128 >= f / 64) ? (bf16)wk[idx] : (bf16)0.f;
    }
}

// ============================================================
// Pack x (fp32 NCHW) -> Xp bf16 [p=(b,y,w)][k=768]
// ============================================================
__global__ void pack_x(const float* __restrict__ x, bf16* __restrict__ Xp) {
    __shared__ float tile[64][65];
    int b = blockIdx.x >> 6, y = blockIdx.x & 63;
    const float* xb = x + ((size_t)b * CINCH * HH + y) * WW;
    bf16* Xrow = Xp + ((size_t)b * HH * WW + (size_t)y * WW) * KI2S;
    for (int ic0 = 0; ic0 < CINCH; ic0 += 64) {
        for (int rep = 0; rep < 16; ++rep) {
            int idx = rep * 256 + threadIdx.x;
            int i = idx >> 6, w = idx & 63;
            tile[i][w] = xb[(size_t)(ic0 + i) * (HH * WW) + w];
        }
        __syncthreads();
        for (int rep = 0; rep < 16; ++rep) {
            int idx = rep * 256 + threadIdx.x;
            int w = idx >> 6, i = idx & 63;
            Xrow[(size_t)w * KI2S + CINCH + ic0 + i] = (bf16)tile[i][w];
            Xrow[(size_t)w * KI2S + ic0 + i] = (w == 0) ? (bf16)0.f : (bf16)tile[i][w - 1];
        }
        __syncthreads();
    }
}

// ============================================================
// i2s GEMM: Hbuf[c'][p] = sum_k WpA[c'][k] * Xp[p][k]
// Staging via global_load_lds width=16: the XOR swizzle is applied on the
// per-lane GLOBAL source address (c = slot ^ (row&7)); the LDS destination
// is linear in L (wave-uniform base + lane*16B), so layout in As/Bs is
// byte-identical to the verified reg-staged version. MFMA loop unchanged.
// ============================================================
__global__ __launch_bounds__(256) void gemm_i2s(const bf16* __restrict__ A,
                                                const bf16* __restrict__ B,
                                                bf16* __restrict__ Hout) {
    __shared__ __align__(16) bf16 As[128 * 64];
    __shared__ __align__(16) bf16 Bs[128 * 64];
    const int m0 = blockIdx.y * 128;
    const int p0 = blockIdx.x * 128;
    const int tid = threadIdx.x;
    const int lane = tid & 63, wid = tid >> 6;
    const int quad = lane >> 4, col = lane & 15;
    const int mhalf = (wid & 1) * 64, nhalf = (wid >> 1) * 64;
    f32x4 acc[4][4] = {};
    for (int k0 = 0; k0 < KI2S; k0 += 64) {
        #pragma unroll
        for (int r = 0; r < 4; ++r) {
            int L = r * 256 + tid;
            int row = L >> 3, slot = L & 7;
            int c = slot ^ (row & 7);
            const bf16* srcA = &A[(size_t)(m0 + row) * KI2S + k0 + c * 8];
            const bf16* srcB = &B[(size_t)(p0 + row) * KI2S + k0 + c * 8];
            // wave-uniform LDS base; HW writes lane L at base + lane*16B == As[L*8]
            bf16* dstA = As + (size_t)(r * 256 + wid * 64) * 8;
            bf16* dstB = Bs + (size_t)(r * 256 + wid * 64) * 8;
            __builtin_amdgcn_global_load_lds(
                (const __attribute__((address_space(1))) void*)srcA,
                (__attribute__((address_space(3))) void*)dstA, 16, 0, 0);
            __builtin_amdgcn_global_load_lds(
                (const __attribute__((address_space(1))) void*)srcB,
                (__attribute__((address_space(3))) void*)dstB, 16, 0, 0);
        }
        __syncthreads();   // drains vmcnt (global_load_lds) before LDS reads
        for (int kk = 0; kk < 2; ++kk) {
            bf16x8 af[4], bfv[4];
            for (int mt = 0; mt < 4; ++mt) {
                int row = mhalf + mt * 16 + col;
                int slot = (kk * 4 + quad) ^ (row & 7);
                af[mt] = *(const bf16x8*)(&As[row * 64 + slot * 8]);
            }
            for (int nt = 0; nt < 4; ++nt) {
                int row = nhalf + nt * 16 + col;
                int slot = (kk * 4 + quad) ^ (row & 7);
                bfv[nt] = *(const bf16x8*)(&Bs[row * 64 + slot * 8]);
            }
            for (int mt = 0; mt < 4; ++mt)
                for (int nt = 0; nt < 4; ++nt)
                    acc[mt][nt] = __builtin_amdgcn_mfma_f32_16x16x32_bf16(
                        af[mt], bfv[nt], acc[mt][nt], 0, 0, 0);
        }
        __syncthreads();
    }
    for (int mt = 0; mt < 4; ++mt)
        for (int nt = 0; nt < 4; ++nt) {
            int m = m0 + mhalf + mt * 16 + quad * 4;
            int p = p0 + nhalf + nt * 16 + col;
            for (int r = 0; r < 4; ++r)
                Hout[(size_t)(m + r) * NP + p] = (bf16)acc[mt][nt][r];
        }
}

// ============================================================
// Cooperative row scan: 192 blocks = 16 batches x 12 feature-chunks(16f).
// Fence-free protocol (verified R1):
//  - h exchange + counters go through IC-coherent relaxed atomics only
//    (no wbl2/inv on the per-row path).
//  - arrival: per-wave vmcnt(0) drain of its sc1 publish stores, then
//    lane0 count. Target = 48 arrivals/row per batch.
//  - skip GEMM (reads hlds = h(y-1), untouched by LSTM which writes a
//    separate hnew buffer) runs in the spin shadow; Hbuf gate-bias
//    prefetch for row y+1 is issued before the spin.
// ============================================================
__global__ __launch_bounds__(256) void scan_kernel(
    const bf16* __restrict__ Hbuf,   // [768][65536]
    const bf16* __restrict__ Ws2s,   // [768][576]
    const bf16* __restrict__ Wskip,  // [384][192]
    const float* __restrict__ x,
    const float* __restrict__ b_skip,
    float* __restrict__ out,
    bf16* __restrict__ hg,           // [3][16][66*192]
    unsigned* __restrict__ cnt) {    // [16][32] padded counters
    cooperative_groups::grid_group grid = cooperative_groups::this_grid();
    __shared__ __align__(16) bf16 hlds[66 * 200];   // staged full h row (halo idx)
    __shared__ __align__(16) bf16 hnew[64 * 20];    // own 16f slice of h(y)
    const int bid = blockIdx.x;
    const int b = (bid & 7) * 2 + (bid / 96);   // same-batch blocks share bid%8
    const int j = (bid >> 3) % 12;
    const int tid = threadIdx.x, lane = tid & 63, wid = tid >> 6;
    const int quad = lane >> 4, col = lane & 15;

    // ---- init: zero hg + counters (plain stores; grid.sync's fences push
    // them to IC) + zero hlds (h(-1) = 0) ----
    {
        const int total = 3 * 16 * 66 * 192 / 2;   // dwords
        for (int i = bid * 256 + tid; i < total; i += NBLK * 256)
            ((unsigned*)hg)[i] = 0u;
        if (tid < 32) cnt[(bid % 16) * 32 + tid] = 0u;
        for (int i = tid; i < 66 * 100; i += 256) ((unsigned*)hlds)[i] = 0u;
    }
    // persistent A fragments
    bf16x8 Ag[18];
    {
        int f = 16 * j + wid * 4 + (col >> 2), q = col & 3;
        const bf16* Arow = Ws2s + (size_t)(q * 192 + f) * KS2S + quad * 8;
        for (int kc = 0; kc < 18; ++kc) Ag[kc] = *(const bf16x8*)(Arow + kc * 32);
    }
    bf16x8 Ak[6];
    const int mtk = wid & 1, ntk0 = (wid >> 1) * 2;
    {
        int co = 32 * j + mtk * 16 + col;
        const bf16* Krow = Wskip + (size_t)co * FEAT + quad * 8;
        for (int kc = 0; kc < 6; ++kc) Ak[kc] = *(const bf16x8*)(Krow + kc * 32);
    }
    const int fmine = 16 * j + wid * 4 + quad;
    const int lf = wid * 4 + quad;              // local feature 0..15
    float cstate[4] = {0.f, 0.f, 0.f, 0.f};
    unsigned* mycnt = cnt + b * 32;
    grid.sync();   // one-time: init visibility (its fences flush zeros to IC)

    const size_t pbase = (size_t)b * HH * WW;
    float hadd[4][4];
    {   // prefetch Hbuf gate biases for row 0
        for (int nt = 0; nt < 4; ++nt) {
            int w = nt * 16 + col;
            for (int r = 0; r < 4; ++r)
                hadd[nt][r] = (float)Hbuf[(size_t)(r * FEAT + fmine) * NP + pbase + w];
        }
    }

    for (int y = 0; y < 64; ++y) {
        // ---- gates GEMM: s = Ws2s_slice * im2col(h(y-1)) ----
        f32x4 acc[4] = {};
        for (int kc = 0; kc < 18; ++kc) {
            int k0 = kc * 32 + quad * 8;
            int t = k0 / FEAT, f = k0 % FEAT;
            for (int nt = 0; nt < 4; ++nt) {
                int w = nt * 16 + col;
                bf16x8 bfr = *(const bf16x8*)(&hlds[(w + t) * 200 + f]);
                acc[nt] = __builtin_amdgcn_mfma_f32_16x16x32_bf16(Ag[kc], bfr, acc[nt], 0, 0, 0);
            }
        }
        // ---- LSTM update -> hnew (hlds stays = h(y-1) for skip GEMM) ----
        for (int nt = 0; nt < 4; ++nt) {
            int w = nt * 16 + col;
            float so = acc[nt][0] + hadd[nt][0];
            float sf = acc[nt][1] + hadd[nt][1];
            float si = acc[nt][2] + hadd[nt][2];
            float sg = acc[nt][3] + hadd[nt][3];
            float go = sigm_fast(so);
            float gf = sigm_fast(sf);
            float gi = sigm_fast(si);
            float gg = sigm_fast(sg);
            float cc = gf * cstate[nt] + gi * gg;
            cstate[nt] = cc;
            hnew[w * 20 + lf] = (bf16)(go * tanh_fast(cc));
        }
        __syncthreads();   // hnew complete across threads

        // ---- publish own 16f slice of h(y) -> hg[y%3][b] (IC stores) ----
        {
            bf16* dst = hg + ((size_t)(y % 3) * 16 + b) * (66 * 192);
            int w = tid >> 2, fo = (tid & 3) * 4;
            u64 v = *(const u64*)(&hnew[w * 20 + fo]);
            ic_store64((u64*)(dst + (size_t)(w + 1) * 192 + 16 * j + fo), v);
        }
        // per-wave arrival: drain own sc1 stores to IC, then count.
        asm volatile("s_waitcnt vmcnt(0)" ::: "memory");
        if (lane == 0)
            __hip_atomic_fetch_add(mycnt, 1u, __ATOMIC_RELAXED, __HIP_MEMORY_SCOPE_AGENT);

        // ---- prefetch Hbuf gate biases for row y+1 (hides HBM latency
        // under skip GEMM + spin + stage) ----
        if (y < 63) {
            const size_t prow = pbase + (size_t)(y + 1) * WW;
            for (int nt = 0; nt < 4; ++nt) {
                int w = nt * 16 + col;
                for (int r = 0; r < 4; ++r)
                    hadd[nt][r] = (float)Hbuf[(size_t)(r * FEAT + fmine) * NP + prow + w];
            }
        }

        // ---- skip GEMM + residual out for row y-1 (spin shadow) ----
        if (y > 0) {
            const int ym = y - 1;
            f32x4 acc2[2] = {};
            for (int kc = 0; kc < 6; ++kc)
                for (int i = 0; i < 2; ++i) {
                    int w = (ntk0 + i) * 16 + col;
                    bf16x8 bfr = *(const bf16x8*)(&hlds[(w + 1) * 200 + kc * 32 + quad * 8]);
                    acc2[i] = __builtin_amdgcn_mfma_f32_16x16x32_bf16(Ak[kc], bfr, acc2[i], 0, 0, 0);
                }
            for (int r = 0; r < 4; ++r) {
                int co = 32 * j + mtk * 16 + quad * 4 + r;
                float bs = b_skip[co];
                for (int i = 0; i < 2; ++i) {
                    int w = (ntk0 + i) * 16 + col;
                    size_t xi = ((size_t)(b * CINCH + co) * HH + ym) * WW + w;
                    out[xi] = x[xi] + bs + acc2[i][r];
                }
            }
        }

        // ---- wait for all 48 wave-arrivals of this batch (row y) ----
        if (tid == 0) {
            unsigned target = 48u * (unsigned)(y + 1);
            while (__hip_atomic_load(mycnt, __ATOMIC_RELAXED, __HIP_MEMORY_SCOPE_AGENT) < target)
                __builtin_amdgcn_s_sleep(1);
        }
        __syncthreads();   // release; also orders prior hlds reads before restage

        // ---- stage h(y) -> hlds (IC loads, 8B units) ----
        {
            const u64* src = (const u64*)(hg + ((size_t)(y % 3) * 16 + b) * (66 * 192));
            #pragma unroll
            for (int it = 0; it < 13; ++it) {
                int c = it * 256 + tid;
                if (c < 66 * 48) {
                    u64 v = ic_load64(src + c);
                    int w = c / 48, fc = c % 48;
                    *(u64*)(&hlds[w * 200 + fc * 4]) = v;
                }
            }
        }
        __syncthreads();
    }

    // ---- epilogue: skip GEMM + residual for row 63 (hlds = h(63)) ----
    {
        const int ym = 63;
        f32x4 acc2[2] = {};
        for (int kc = 0; kc < 6; ++kc)
            for (int i = 0; i < 2; ++i) {
                int w = (ntk0 + i) * 16 + col;
                bf16x8 bfr = *(const bf16x8*)(&hlds[(w + 1) * 200 + kc * 32 + quad * 8]);
                acc2[i] = __builtin_amdgcn_mfma_f32_16x16x32_bf16(Ak[kc], bfr, acc2[i], 0, 0, 0);
            }
        for (int r = 0; r < 4; ++r) {
            int co = 32 * j + mtk * 16 + quad * 4 + r;
            float bs = b_skip[co];
            for (int i = 0; i < 2; ++i) {
                int w = (ntk0 + i) * 16 + col;
                size_t xi = ((size_t)(b * CINCH + co) * HH + ym) * WW + w;
                out[xi] = x[xi] + bs + acc2[i][r];
            }
        }
    }
}

// ============================================================
extern "C" void kernel_launch(void* const* d_in, const int* in_sizes, int n_in,
                              void* d_out, int out_size, void* d_ws, size_t ws_size,
                              hipStream_t stream) {
    const float* x      = (const float*)d_in[0];
    const float* w_i2s  = (const float*)d_in[1];
    const float* w_s2s  = (const float*)d_in[2];
    const float* w_skip = (const float*)d_in[3];
    const float* b_skip = (const float*)d_in[4];
    float* out = (float*)d_out;

    char* ws = (char*)d_ws;
    const size_t HBUF_B = (size_t)CGATE * NP * 2;        // 100,663,296
    bf16* Hbuf = (bf16*)ws;
    size_t off = HBUF_B;
    bf16* WpA  = (bf16*)(ws + off); off += (size_t)CGATE * KI2S * 2;
    bf16* WpS  = (bf16*)(ws + off); off += (size_t)CGATE * KS2S * 2;
    bf16* WpK  = (bf16*)(ws + off); off += (size_t)CINCH * FEAT * 2;
    bf16* hg   = (bf16*)(ws + off); off += (size_t)3 * 16 * 66 * 192 * 2;
    unsigned* cnt = (unsigned*)(ws + off);               // 16*32 u32 = 2 KB
    bf16* Xp   = (bf16*)d_out;   // im2col scratch in d_out; dead before scan writes out

    pack_weights<<<256, 256, 0, stream>>>(w_i2s, w_s2s, w_skip, WpA, WpS, WpK);
    pack_x<<<BATCH * HH, 256, 0, stream>>>(x, Xp);
    dim3 g3(NP / 128, CGATE / 128);
    gemm_i2s<<<g3, 256, 0, stream>>>(WpA, Xp, Hbuf);

    void* args[] = { (void*)&Hbuf, (void*)&WpS, (void*)&WpK,
                     (void*)&x, (void*)&b_skip, (void*)&out, (void*)&hg, (void*)&cnt };
    hipLaunchCooperativeKernel((const void*)scan_kernel, dim3(NBLK), dim3(256),
                               args, 0, stream);
}

// Round 6
// 753.432 us; speedup vs baseline: 1.6702x; 1.0246x over previous
//
#include <hip/hip_runtime.h>
#include <hip/hip_cooperative_groups.h>
#include <cmath>

// ---------------- problem constants ----------------
#define FEAT  192
#define CINCH 384          // CIN
#define CGATE 768
#define BATCH 16
#define HH    64
#define WW    64
#define NP    (BATCH*HH*WW)   // 65536 flattened (b,y,w)
#define KI2S  768             // 384 ic * 2 live taps
#define KS2S  576             // 192 feat * 3 taps
#define NBLK  192             // scan blocks: 16 batches x 12 f-chunks

using bf16   = __bf16;
using bf16x8 = __attribute__((ext_vector_type(8))) __bf16;
using bf16x4 = __attribute__((ext_vector_type(4))) __bf16;
using f32x4  = __attribute__((ext_vector_type(4))) float;
typedef unsigned long long u64;

// ---------------------------------------------------------------
// IC-coherent accessors: relaxed agent-scope atomics compile to plain
// global_load/store with sc0/sc1 flags (bypass L1+L2, hit Infinity
// Cache = the cross-XCD coherence point). NO buffer_wbl2 / buffer_inv
// cache-wide maintenance ops are emitted. Visibility rule: sc1 store
// completion (vmcnt==0, provided by __syncthreads' drain) => visible
// at IC => visible to any sc1 load.
// ---------------------------------------------------------------
__device__ __forceinline__ void ic_store64(u64* p, u64 v) {
    __hip_atomic_store(p, v, __ATOMIC_RELAXED, __HIP_MEMORY_SCOPE_AGENT);
}
__device__ __forceinline__ u64 ic_load64(const u64* p) {
    return __hip_atomic_load(p, __ATOMIC_RELAXED, __HIP_MEMORY_SCOPE_AGENT);
}
__device__ __forceinline__ void ic_store32(unsigned* p, unsigned v) {
    __hip_atomic_store(p, v, __ATOMIC_RELAXED, __HIP_MEMORY_SCOPE_AGENT);
}
__device__ __forceinline__ unsigned ic_load32(const unsigned* p) {
    return __hip_atomic_load(p, __ATOMIC_RELAXED, __HIP_MEMORY_SCOPE_AGENT);
}

__device__ __forceinline__ float sigm_fast(float v) {
    return __builtin_amdgcn_rcpf(1.f + __expf(-v));
}
__device__ __forceinline__ float tanh_fast(float v) {
    // 1 - 2/(1+e^{2v}); saturates correctly for |v| large (exp->inf/0)
    return 1.f - 2.f * __builtin_amdgcn_rcpf(1.f + __expf(2.f * v));
}

// ============================================================
// Pack weights into bf16 GEMM operand layouts (A row-major, k contiguous).
// ============================================================
__global__ void pack_weights(const float* __restrict__ wi, const float* __restrict__ ws,
                             const float* __restrict__ wk,
                             bf16* __restrict__ WpA, bf16* __restrict__ WpS,
                             bf16* __restrict__ WpK) {
    int tid = blockIdx.x * 256 + threadIdx.x;
    int stride = gridDim.x * 256;
    for (int idx = tid; idx < CGATE * KI2S; idx += stride) {
        int cp = idx / KI2S, k = idx % KI2S;
        int q = cp / 192, r = cp % 192, g = r / 64, f = r % 64;
        int c = g * 256 + q * 64 + f;             // original (pre-shuffle) out channel
        float v;
        if (k < CINCH) {
            v = wi[(c * CINCH + k) * 3 + 0];      // tap0: full
        } else {
            int ic = k - CINCH;                   // tap1: causal group mask
            v = (g >= ic / 128) ? wi[(c * CINCH + ic) * 3 + 1] : 0.f;
        }
        WpA[idx] = (bf16)v;
    }
    for (int idx = tid; idx < CGATE * KS2S; idx += stride) {
        int oc = idx / KS2S, k = idx % KS2S;
        int t = k / FEAT, f = k % FEAT;
        WpS[idx] = (bf16)ws[(oc * FEAT + f) * 3 + t];
    }
    for (int idx = tid; idx < CINCH * FEAT; idx += stride) {
        int co = idx / FEAT, f = idx % FEAT;
        WpK[idx] = (co / 128 >= f / 64) ? (bf16)wk[idx] : (bf16)0.f;
    }
}

// ============================================================
// Pack x (fp32 NCHW) -> Xp bf16 [p=(b,y,w)][k=768]
// ============================================================
__global__ void pack_x(const float* __restrict__ x, bf16* __restrict__ Xp) {
    __shared__ float tile[64][65];
    int b = blockIdx.x >> 6, y = blockIdx.x & 63;
    const float* xb = x + ((size_t)b * CINCH * HH + y) * WW;
    bf16* Xrow = Xp + ((size_t)b * HH * WW + (size_t)y * WW) * KI2S;
    for (int ic0 = 0; ic0 < CINCH; ic0 += 64) {
        for (int rep = 0; rep < 16; ++rep) {
            int idx = rep * 256 + threadIdx.x;
            int i = idx >> 6, w = idx & 63;
            tile[i][w] = xb[(size_t)(ic0 + i) * (HH * WW) + w];
        }
        __syncthreads();
        for (int rep = 0; rep < 16; ++rep) {
            int idx = rep * 256 + threadIdx.x;
            int w = idx >> 6, i = idx & 63;
            Xrow[(size_t)w * KI2S + CINCH + ic0 + i] = (bf16)tile[i][w];
            Xrow[(size_t)w * KI2S + ic0 + i] = (w == 0) ? (bf16)0.f : (bf16)tile[i][w - 1];
        }
        __syncthreads();
    }
}

// ============================================================
// i2s GEMM: Hbuf[c'][p] = sum_k WpA[c'][k] * Xp[p][k]
// Staging via global_load_lds width=16 (verified R5): XOR swizzle applied
// on the per-lane GLOBAL source address; LDS destination linear in L.
// ============================================================
__global__ __launch_bounds__(256) void gemm_i2s(const bf16* __restrict__ A,
                                                const bf16* __restrict__ B,
                                                bf16* __restrict__ Hout) {
    __shared__ __align__(16) bf16 As[128 * 64];
    __shared__ __align__(16) bf16 Bs[128 * 64];
    const int m0 = blockIdx.y * 128;
    const int p0 = blockIdx.x * 128;
    const int tid = threadIdx.x;
    const int lane = tid & 63, wid = tid >> 6;
    const int quad = lane >> 4, col = lane & 15;
    const int mhalf = (wid & 1) * 64, nhalf = (wid >> 1) * 64;
    f32x4 acc[4][4] = {};
    for (int k0 = 0; k0 < KI2S; k0 += 64) {
        #pragma unroll
        for (int r = 0; r < 4; ++r) {
            int L = r * 256 + tid;
            int row = L >> 3, slot = L & 7;
            int c = slot ^ (row & 7);
            const bf16* srcA = &A[(size_t)(m0 + row) * KI2S + k0 + c * 8];
            const bf16* srcB = &B[(size_t)(p0 + row) * KI2S + k0 + c * 8];
            bf16* dstA = As + (size_t)(r * 256 + wid * 64) * 8;
            bf16* dstB = Bs + (size_t)(r * 256 + wid * 64) * 8;
            __builtin_amdgcn_global_load_lds(
                (const __attribute__((address_space(1))) void*)srcA,
                (__attribute__((address_space(3))) void*)dstA, 16, 0, 0);
            __builtin_amdgcn_global_load_lds(
                (const __attribute__((address_space(1))) void*)srcB,
                (__attribute__((address_space(3))) void*)dstB, 16, 0, 0);
        }
        __syncthreads();   // drains vmcnt (global_load_lds) before LDS reads
        for (int kk = 0; kk < 2; ++kk) {
            bf16x8 af[4], bfv[4];
            for (int mt = 0; mt < 4; ++mt) {
                int row = mhalf + mt * 16 + col;
                int slot = (kk * 4 + quad) ^ (row & 7);
                af[mt] = *(const bf16x8*)(&As[row * 64 + slot * 8]);
            }
            for (int nt = 0; nt < 4; ++nt) {
                int row = nhalf + nt * 16 + col;
                int slot = (kk * 4 + quad) ^ (row & 7);
                bfv[nt] = *(const bf16x8*)(&Bs[row * 64 + slot * 8]);
            }
            for (int mt = 0; mt < 4; ++mt)
                for (int nt = 0; nt < 4; ++nt)
                    acc[mt][nt] = __builtin_amdgcn_mfma_f32_16x16x32_bf16(
                        af[mt], bfv[nt], acc[mt][nt], 0, 0, 0);
        }
        __syncthreads();
    }
    for (int mt = 0; mt < 4; ++mt)
        for (int nt = 0; nt < 4; ++nt) {
            int m = m0 + mhalf + mt * 16 + quad * 4;
            int p = p0 + nhalf + nt * 16 + col;
            for (int r = 0; r < 4; ++r)
                Hout[(size_t)(m + r) * NP + p] = (bf16)acc[mt][nt][r];
        }
}

// ============================================================
// Cooperative row scan: 192 blocks = 16 batches x 12 feature-chunks(16f).
// Flag-based fence-free protocol (replaces 48 same-address fetch_adds,
// which serialize at the IC atomic unit ~70-100ns each = ~4us/row):
//  - producer: publish h-slice (sc1 stores) -> __syncthreads (compiler
//    emits vmcnt(0): ALL waves' publishes visible at IC) -> tid0 plain
//    sc1 store of flag[b][j] = y+1. One writer per flag, no RMW.
//  - consumer: lanes 0-11 load the 12 flags IN PARALLEL, ballot-check
//    all >= y+1. One IC round trip per poll, no serialization.
// ============================================================
__global__ __launch_bounds__(256) void scan_kernel(
    const bf16* __restrict__ Hbuf,   // [768][65536]
    const bf16* __restrict__ Ws2s,   // [768][576]
    const bf16* __restrict__ Wskip,  // [384][192]
    const float* __restrict__ x,
    const float* __restrict__ b_skip,
    float* __restrict__ out,
    bf16* __restrict__ hg,           // [3][16][66*192]
    unsigned* __restrict__ cnt) {    // [16][32] flags: cnt[b*32+j] = rows done
    cooperative_groups::grid_group grid = cooperative_groups::this_grid();
    __shared__ __align__(16) bf16 hlds[66 * 200];   // staged full h row (halo idx)
    __shared__ __align__(16) bf16 hnew[64 * 20];    // own 16f slice of h(y)
    const int bid = blockIdx.x;
    const int b = (bid & 7) * 2 + (bid / 96);   // same-batch blocks share bid%8
    const int j = (bid >> 3) % 12;
    const int tid = threadIdx.x, lane = tid & 63, wid = tid >> 6;
    const int quad = lane >> 4, col = lane & 15;

    // ---- init: zero hg + flags (plain stores; grid.sync's fences push
    // them to IC) + zero hlds (h(-1) = 0) ----
    {
        const int total = 3 * 16 * 66 * 192 / 2;   // dwords
        for (int i = bid * 256 + tid; i < total; i += NBLK * 256)
            ((unsigned*)hg)[i] = 0u;
        if (tid < 32) cnt[(bid % 16) * 32 + tid] = 0u;
        for (int i = tid; i < 66 * 100; i += 256) ((unsigned*)hlds)[i] = 0u;
    }
    // persistent A fragments
    bf16x8 Ag[18];
    {
        int f = 16 * j + wid * 4 + (col >> 2), q = col & 3;
        const bf16* Arow = Ws2s + (size_t)(q * 192 + f) * KS2S + quad * 8;
        for (int kc = 0; kc < 18; ++kc) Ag[kc] = *(const bf16x8*)(Arow + kc * 32);
    }
    bf16x8 Ak[6];
    const int mtk = wid & 1, ntk0 = (wid >> 1) * 2;
    {
        int co = 32 * j + mtk * 16 + col;
        const bf16* Krow = Wskip + (size_t)co * FEAT + quad * 8;
        for (int kc = 0; kc < 6; ++kc) Ak[kc] = *(const bf16x8*)(Krow + kc * 32);
    }
    const int fmine = 16 * j + wid * 4 + quad;
    const int lf = wid * 4 + quad;              // local feature 0..15
    float cstate[4] = {0.f, 0.f, 0.f, 0.f};
    unsigned* myflags = cnt + b * 32;           // 12 flags, one 64B line
    grid.sync();   // one-time: init visibility (its fences flush zeros to IC)

    const size_t pbase = (size_t)b * HH * WW;
    float hadd[4][4];
    {   // prefetch Hbuf gate biases for row 0
        for (int nt = 0; nt < 4; ++nt) {
            int w = nt * 16 + col;
            for (int r = 0; r < 4; ++r)
                hadd[nt][r] = (float)Hbuf[(size_t)(r * FEAT + fmine) * NP + pbase + w];
        }
    }

    for (int y = 0; y < 64; ++y) {
        // ---- gates GEMM: s = Ws2s_slice * im2col(h(y-1)) ----
        f32x4 acc[4] = {};
        for (int kc = 0; kc < 18; ++kc) {
            int k0 = kc * 32 + quad * 8;
            int t = k0 / FEAT, f = k0 % FEAT;
            for (int nt = 0; nt < 4; ++nt) {
                int w = nt * 16 + col;
                bf16x8 bfr = *(const bf16x8*)(&hlds[(w + t) * 200 + f]);
                acc[nt] = __builtin_amdgcn_mfma_f32_16x16x32_bf16(Ag[kc], bfr, acc[nt], 0, 0, 0);
            }
        }
        // ---- LSTM update -> hnew (hlds stays = h(y-1) for skip GEMM) ----
        for (int nt = 0; nt < 4; ++nt) {
            int w = nt * 16 + col;
            float so = acc[nt][0] + hadd[nt][0];
            float sf = acc[nt][1] + hadd[nt][1];
            float si = acc[nt][2] + hadd[nt][2];
            float sg = acc[nt][3] + hadd[nt][3];
            float go = sigm_fast(so);
            float gf = sigm_fast(sf);
            float gi = sigm_fast(si);
            float gg = sigm_fast(sg);
            float cc = gf * cstate[nt] + gi * gg;
            cstate[nt] = cc;
            hnew[w * 20 + lf] = (bf16)(go * tanh_fast(cc));
        }
        __syncthreads();   // S1: hnew complete across threads

        // ---- publish own 16f slice of h(y) -> hg[y%3][b] (IC stores) ----
        {
            bf16* dst = hg + ((size_t)(y % 3) * 16 + b) * (66 * 192);
            int w = tid >> 2, fo = (tid & 3) * 4;
            u64 v = *(const u64*)(&hnew[w * 20 + fo]);
            ic_store64((u64*)(dst + (size_t)(w + 1) * 192 + 16 * j + fo), v);
        }
        __syncthreads();   // S2: vmcnt(0) drain => ALL publishes visible at IC
        // single-writer flag store (no RMW, no serialization)
        if (tid == 0) ic_store32(&myflags[j], (unsigned)(y + 1));

        // ---- prefetch Hbuf gate biases for row y+1 (spin shadow) ----
        if (y < 63) {
            const size_t prow = pbase + (size_t)(y + 1) * WW;
            for (int nt = 0; nt < 4; ++nt) {
                int w = nt * 16 + col;
                for (int r = 0; r < 4; ++r)
                    hadd[nt][r] = (float)Hbuf[(size_t)(r * FEAT + fmine) * NP + prow + w];
            }
        }

        // ---- skip GEMM + residual out for row y-1 (spin shadow) ----
        if (y > 0) {
            const int ym = y - 1;
            f32x4 acc2[2] = {};
            for (int kc = 0; kc < 6; ++kc)
                for (int i = 0; i < 2; ++i) {
                    int w = (ntk0 + i) * 16 + col;
                    bf16x8 bfr = *(const bf16x8*)(&hlds[(w + 1) * 200 + kc * 32 + quad * 8]);
                    acc2[i] = __builtin_amdgcn_mfma_f32_16x16x32_bf16(Ak[kc], bfr, acc2[i], 0, 0, 0);
                }
            for (int r = 0; r < 4; ++r) {
                int co = 32 * j + mtk * 16 + quad * 4 + r;
                float bs = b_skip[co];
                for (int i = 0; i < 2; ++i) {
                    int w = (ntk0 + i) * 16 + col;
                    size_t xi = ((size_t)(b * CINCH + co) * HH + ym) * WW + w;
                    out[xi] = x[xi] + bs + acc2[i][r];
                }
            }
        }
        __syncthreads();   // S3: hlds reads (gates+skip) done before restage

        // ---- spin: all 12 flags >= y+1 (parallel loads, ballot check) ----
        {
            const unsigned tgt = (unsigned)(y + 1);
            while (true) {
                unsigned v = (lane < 12) ? ic_load32(&myflags[lane]) : tgt;
                if (__ballot(v >= tgt) == ~0ull) break;
                __builtin_amdgcn_s_sleep(1);
            }
            asm volatile("" ::: "memory");   // keep stage loads after the poll
        }

        // ---- stage h(y) -> hlds (IC loads, 8B units) ----
        {
            const u64* src = (const u64*)(hg + ((size_t)(y % 3) * 16 + b) * (66 * 192));
            #pragma unroll
            for (int it = 0; it < 13; ++it) {
                int c = it * 256 + tid;
                if (c < 66 * 48) {
                    u64 v = ic_load64(src + c);
                    int w = c / 48, fc = c % 48;
                    *(u64*)(&hlds[w * 200 + fc * 4]) = v;
                }
            }
        }
        __syncthreads();   // S4: stage visible to all
    }

    // ---- epilogue: skip GEMM + residual for row 63 (hlds = h(63)) ----
    {
        const int ym = 63;
        f32x4 acc2[2] = {};
        for (int kc = 0; kc < 6; ++kc)
            for (int i = 0; i < 2; ++i) {
                int w = (ntk0 + i) * 16 + col;
                bf16x8 bfr = *(const bf16x8*)(&hlds[(w + 1) * 200 + kc * 32 + quad * 8]);
                acc2[i] = __builtin_amdgcn_mfma_f32_16x16x32_bf16(Ak[kc], bfr, acc2[i], 0, 0, 0);
            }
        for (int r = 0; r < 4; ++r) {
            int co = 32 * j + mtk * 16 + quad * 4 + r;
            float bs = b_skip[co];
            for (int i = 0; i < 2; ++i) {
                int w = (ntk0 + i) * 16 + col;
                size_t xi = ((size_t)(b * CINCH + co) * HH + ym) * WW + w;
                out[xi] = x[xi] + bs + acc2[i][r];
            }
        }
    }
}

// ============================================================
extern "C" void kernel_launch(void* const* d_in, const int* in_sizes, int n_in,
                              void* d_out, int out_size, void* d_ws, size_t ws_size,
                              hipStream_t stream) {
    const float* x      = (const float*)d_in[0];
    const float* w_i2s  = (const float*)d_in[1];
    const float* w_s2s  = (const float*)d_in[2];
    const float* w_skip = (const float*)d_in[3];
    const float* b_skip = (const float*)d_in[4];
    float* out = (float*)d_out;

    char* ws = (char*)d_ws;
    const size_t HBUF_B = (size_t)CGATE * NP * 2;        // 100,663,296
    bf16* Hbuf = (bf16*)ws;
    size_t off = HBUF_B;
    bf16* WpA  = (bf16*)(ws + off); off += (size_t)CGATE * KI2S * 2;
    bf16* WpS  = (bf16*)(ws + off); off += (size_t)CGATE * KS2S * 2;
    bf16* WpK  = (bf16*)(ws + off); off += (size_t)CINCH * FEAT * 2;
    bf16* hg   = (bf16*)(ws + off); off += (size_t)3 * 16 * 66 * 192 * 2;
    unsigned* cnt = (unsigned*)(ws + off);               // 16*32 u32 = 2 KB
    bf16* Xp   = (bf16*)d_out;   // im2col scratch in d_out; dead before scan writes out

    pack_weights<<<256, 256, 0, stream>>>(w_i2s, w_s2s, w_skip, WpA, WpS, WpK);
    pack_x<<<BATCH * HH, 256, 0, stream>>>(x, Xp);
    dim3 g3(NP / 128, CGATE / 128);
    gemm_i2s<<<g3, 256, 0, stream>>>(WpA, Xp, Hbuf);

    void* args[] = { (void*)&Hbuf, (void*)&WpS, (void*)&WpK,
                     (void*)&x, (void*)&b_skip, (void*)&out, (void*)&hg, (void*)&cnt };
    hipLaunchCooperativeKernel((const void*)scan_kernel, dim3(NBLK), dim3(256),
                               args, 0, stream);
}

// Round 7
// 666.497 us; speedup vs baseline: 1.8881x; 1.1304x over previous
//
#include <hip/hip_runtime.h>
#include <hip/hip_cooperative_groups.h>
#include <cmath>

// ---------------- problem constants ----------------
#define FEAT  192
#define CINCH 384          // CIN
#define CGATE 768
#define BATCH 16
#define HH    64
#define WW    64
#define NP    (BATCH*HH*WW)   // 65536 flattened (b,y,w)
#define KI2S  768             // 384 ic * 2 live taps
#define KS2S  576             // 192 feat * 3 taps
#define NBLK  192             // scan blocks: 16 batches x 12 f-chunks
#define SCANT 512             // scan threads: 8 waves

using bf16   = __bf16;
using bf16x8 = __attribute__((ext_vector_type(8))) __bf16;
using bf16x4 = __attribute__((ext_vector_type(4))) __bf16;
using f32x4  = __attribute__((ext_vector_type(4))) float;
typedef unsigned long long u64;

// ---------------------------------------------------------------
// IC-coherent accessors: relaxed agent-scope atomics compile to plain
// global_load/store with sc0/sc1 flags (bypass L1+L2, hit Infinity
// Cache = the cross-XCD coherence point). No cache-wide wbl2/inv on
// the per-row path. Visibility rule: sc1 store completion (vmcnt==0,
// provided by __syncthreads' drain) => visible at IC => visible to
// any sc1 load.
// ---------------------------------------------------------------
__device__ __forceinline__ void ic_store64(u64* p, u64 v) {
    __hip_atomic_store(p, v, __ATOMIC_RELAXED, __HIP_MEMORY_SCOPE_AGENT);
}
__device__ __forceinline__ u64 ic_load64(const u64* p) {
    return __hip_atomic_load(p, __ATOMIC_RELAXED, __HIP_MEMORY_SCOPE_AGENT);
}
__device__ __forceinline__ void ic_store32(unsigned* p, unsigned v) {
    __hip_atomic_store(p, v, __ATOMIC_RELAXED, __HIP_MEMORY_SCOPE_AGENT);
}
__device__ __forceinline__ unsigned ic_load32(const unsigned* p) {
    return __hip_atomic_load(p, __ATOMIC_RELAXED, __HIP_MEMORY_SCOPE_AGENT);
}

__device__ __forceinline__ float sigm_fast(float v) {
    return __builtin_amdgcn_rcpf(1.f + __expf(-v));
}
__device__ __forceinline__ float tanh_fast(float v) {
    // 1 - 2/(1+e^{2v}); saturates correctly for |v| large (exp->inf/0)
    return 1.f - 2.f * __builtin_amdgcn_rcpf(1.f + __expf(2.f * v));
}

// ============================================================
// Pack weights into bf16 GEMM operand layouts (A row-major, k contiguous).
// ============================================================
__global__ void pack_weights(const float* __restrict__ wi, const float* __restrict__ ws,
                             const float* __restrict__ wk,
                             bf16* __restrict__ WpA, bf16* __restrict__ WpS,
                             bf16* __restrict__ WpK) {
    int tid = blockIdx.x * 256 + threadIdx.x;
    int stride = gridDim.x * 256;
    for (int idx = tid; idx < CGATE * KI2S; idx += stride) {
        int cp = idx / KI2S, k = idx % KI2S;
        int q = cp / 192, r = cp % 192, g = r / 64, f = r % 64;
        int c = g * 256 + q * 64 + f;             // original (pre-shuffle) out channel
        float v;
        if (k < CINCH) {
            v = wi[(c * CINCH + k) * 3 + 0];      // tap0: full
        } else {
            int ic = k - CINCH;                   // tap1: causal group mask
            v = (g >= ic / 128) ? wi[(c * CINCH + ic) * 3 + 1] : 0.f;
        }
        WpA[idx] = (bf16)v;
    }
    for (int idx = tid; idx < CGATE * KS2S; idx += stride) {
        int oc = idx / KS2S, k = idx % KS2S;
        int t = k / FEAT, f = k % FEAT;
        WpS[idx] = (bf16)ws[(oc * FEAT + f) * 3 + t];
    }
    for (int idx = tid; idx < CINCH * FEAT; idx += stride) {
        int co = idx / FEAT, f = idx % FEAT;
        WpK[idx] = (co / 128 >= f / 64) ? (bf16)wk[idx] : (bf16)0.f;
    }
}

// ============================================================
// Pack x (fp32 NCHW) -> Xp bf16 [p=(b,y,w)][k=768]
// ============================================================
__global__ void pack_x(const float* __restrict__ x, bf16* __restrict__ Xp) {
    __shared__ float tile[64][65];
    int b = blockIdx.x >> 6, y = blockIdx.x & 63;
    const float* xb = x + ((size_t)b * CINCH * HH + y) * WW;
    bf16* Xrow = Xp + ((size_t)b * HH * WW + (size_t)y * WW) * KI2S;
    for (int ic0 = 0; ic0 < CINCH; ic0 += 64) {
        for (int rep = 0; rep < 16; ++rep) {
            int idx = rep * 256 + threadIdx.x;
            int i = idx >> 6, w = idx & 63;
            tile[i][w] = xb[(size_t)(ic0 + i) * (HH * WW) + w];
        }
        __syncthreads();
        for (int rep = 0; rep < 16; ++rep) {
            int idx = rep * 256 + threadIdx.x;
            int w = idx >> 6, i = idx & 63;
            Xrow[(size_t)w * KI2S + CINCH + ic0 + i] = (bf16)tile[i][w];
            Xrow[(size_t)w * KI2S + ic0 + i] = (w == 0) ? (bf16)0.f : (bf16)tile[i][w - 1];
        }
        __syncthreads();
    }
}

// ============================================================
// i2s GEMM: Hbuf[c'][p] = sum_k WpA[c'][k] * Xp[p][k]
// Staging via global_load_lds width=16 (verified R5): XOR swizzle applied
// on the per-lane GLOBAL source address; LDS destination linear in L.
// ============================================================
__global__ __launch_bounds__(256) void gemm_i2s(const bf16* __restrict__ A,
                                                const bf16* __restrict__ B,
                                                bf16* __restrict__ Hout) {
    __shared__ __align__(16) bf16 As[128 * 64];
    __shared__ __align__(16) bf16 Bs[128 * 64];
    const int m0 = blockIdx.y * 128;
    const int p0 = blockIdx.x * 128;
    const int tid = threadIdx.x;
    const int lane = tid & 63, wid = tid >> 6;
    const int quad = lane >> 4, col = lane & 15;
    const int mhalf = (wid & 1) * 64, nhalf = (wid >> 1) * 64;
    f32x4 acc[4][4] = {};
    for (int k0 = 0; k0 < KI2S; k0 += 64) {
        #pragma unroll
        for (int r = 0; r < 4; ++r) {
            int L = r * 256 + tid;
            int row = L >> 3, slot = L & 7;
            int c = slot ^ (row & 7);
            const bf16* srcA = &A[(size_t)(m0 + row) * KI2S + k0 + c * 8];
            const bf16* srcB = &B[(size_t)(p0 + row) * KI2S + k0 + c * 8];
            bf16* dstA = As + (size_t)(r * 256 + wid * 64) * 8;
            bf16* dstB = Bs + (size_t)(r * 256 + wid * 64) * 8;
            __builtin_amdgcn_global_load_lds(
                (const __attribute__((address_space(1))) void*)srcA,
                (__attribute__((address_space(3))) void*)dstA, 16, 0, 0);
            __builtin_amdgcn_global_load_lds(
                (const __attribute__((address_space(1))) void*)srcB,
                (__attribute__((address_space(3))) void*)dstB, 16, 0, 0);
        }
        __syncthreads();   // drains vmcnt (global_load_lds) before LDS reads
        for (int kk = 0; kk < 2; ++kk) {
            bf16x8 af[4], bfv[4];
            for (int mt = 0; mt < 4; ++mt) {
                int row = mhalf + mt * 16 + col;
                int slot = (kk * 4 + quad) ^ (row & 7);
                af[mt] = *(const bf16x8*)(&As[row * 64 + slot * 8]);
            }
            for (int nt = 0; nt < 4; ++nt) {
                int row = nhalf + nt * 16 + col;
                int slot = (kk * 4 + quad) ^ (row & 7);
                bfv[nt] = *(const bf16x8*)(&Bs[row * 64 + slot * 8]);
            }
            for (int mt = 0; mt < 4; ++mt)
                for (int nt = 0; nt < 4; ++nt)
                    acc[mt][nt] = __builtin_amdgcn_mfma_f32_16x16x32_bf16(
                        af[mt], bfv[nt], acc[mt][nt], 0, 0, 0);
        }
        __syncthreads();
    }
    for (int mt = 0; mt < 4; ++mt)
        for (int nt = 0; nt < 4; ++nt) {
            int m = m0 + mhalf + mt * 16 + quad * 4;
            int p = p0 + nhalf + nt * 16 + col;
            for (int r = 0; r < 4; ++r)
                Hout[(size_t)(m + r) * NP + p] = (bf16)acc[mt][nt][r];
        }
}

// ============================================================
// Cooperative row scan: 192 blocks x 512 threads (8 waves).
// Same flag protocol as R6 (verified). Work re-partitioned over 8 waves:
//   wh = wid&3 : m-slice role (4 features x 4 gates), as before
//   wn = wid>>2: n-half (w 0-31 / 32-63)
// Gates: each wave 2 n-tiles (was 4). Skip: each wave 1 (co-half, w-quarter)
// tile (was 2x2). LSTM/prefetch: 2 nt per thread (was 4). Stage: 512-wide.
// Rationale: at 4 waves/CU (1/SIMD) all VALU + LDS latency was serial on
// the row critical path; 8 waves halves the serial span and gives 2/SIMD TLP.
// ============================================================
__global__ __launch_bounds__(SCANT) void scan_kernel(
    const bf16* __restrict__ Hbuf,   // [768][65536]
    const bf16* __restrict__ Ws2s,   // [768][576]
    const bf16* __restrict__ Wskip,  // [384][192]
    const float* __restrict__ x,
    const float* __restrict__ b_skip,
    float* __restrict__ out,
    bf16* __restrict__ hg,           // [3][16][66*192]
    unsigned* __restrict__ cnt) {    // [16][32] flags: cnt[b*32+j] = rows done
    cooperative_groups::grid_group grid = cooperative_groups::this_grid();
    __shared__ __align__(16) bf16 hlds[66 * 200];   // staged full h row (halo idx)
    __shared__ __align__(16) bf16 hnew[64 * 20];    // own 16f slice of h(y)
    const int bid = blockIdx.x;
    const int b = (bid & 7) * 2 + (bid / 96);   // same-batch blocks share bid%8
    const int j = (bid >> 3) % 12;
    const int tid = threadIdx.x, lane = tid & 63, wid = tid >> 6;
    const int quad = lane >> 4, col = lane & 15;
    const int wh = wid & 3;                     // m-slice role
    const int wn = wid >> 2;                    // n-half

    // ---- init: zero hg + flags + hlds (h(-1) = 0) ----
    {
        const int total = 3 * 16 * 66 * 192 / 2;   // dwords
        for (int i = bid * SCANT + tid; i < total; i += NBLK * SCANT)
            ((unsigned*)hg)[i] = 0u;
        if (tid < 32) cnt[(bid % 16) * 32 + tid] = 0u;
        for (int i = tid; i < 66 * 100; i += SCANT) ((unsigned*)hlds)[i] = 0u;
    }
    // persistent A fragments (gates use wh; waves wn=0/1 duplicate loads)
    bf16x8 Ag[18];
    {
        int f = 16 * j + wh * 4 + (col >> 2), q = col & 3;
        const bf16* Arow = Ws2s + (size_t)(q * 192 + f) * KS2S + quad * 8;
        for (int kc = 0; kc < 18; ++kc) Ag[kc] = *(const bf16x8*)(Arow + kc * 32);
    }
    bf16x8 Ak[6];
    const int mtk = wid & 1, ntk = wid >> 1;    // skip: co-half x w-quarter
    {
        int co = 32 * j + mtk * 16 + col;
        const bf16* Krow = Wskip + (size_t)co * FEAT + quad * 8;
        for (int kc = 0; kc < 6; ++kc) Ak[kc] = *(const bf16x8*)(Krow + kc * 32);
    }
    const int fmine = 16 * j + wh * 4 + quad;
    const int lf = wh * 4 + quad;               // local feature 0..15
    float cstate[2] = {0.f, 0.f};
    unsigned* myflags = cnt + b * 32;           // 12 flags, one 64B line
    grid.sync();   // one-time: init visibility (its fences flush zeros to IC)

    const size_t pbase = (size_t)b * HH * WW;
    float hadd[2][4];
    {   // prefetch Hbuf gate biases for row 0 (this thread's 2 nt)
        for (int i = 0; i < 2; ++i) {
            int w = (wn * 2 + i) * 16 + col;
            for (int r = 0; r < 4; ++r)
                hadd[i][r] = (float)Hbuf[(size_t)(r * FEAT + fmine) * NP + pbase + w];
        }
    }

    for (int y = 0; y < 64; ++y) {
        // ---- gates GEMM: s = Ws2s_slice * im2col(h(y-1)), 2 n-tiles/wave ----
        f32x4 acc[2] = {};
        for (int kc = 0; kc < 18; ++kc) {
            int k0 = kc * 32 + quad * 8;
            int t = k0 / FEAT, f = k0 % FEAT;
            #pragma unroll
            for (int i = 0; i < 2; ++i) {
                int w = (wn * 2 + i) * 16 + col;
                bf16x8 bfr = *(const bf16x8*)(&hlds[(w + t) * 200 + f]);
                acc[i] = __builtin_amdgcn_mfma_f32_16x16x32_bf16(Ag[kc], bfr, acc[i], 0, 0, 0);
            }
        }
        // ---- LSTM update -> hnew (hlds stays = h(y-1) for skip GEMM) ----
        #pragma unroll
        for (int i = 0; i < 2; ++i) {
            int w = (wn * 2 + i) * 16 + col;
            float so = acc[i][0] + hadd[i][0];
            float sf = acc[i][1] + hadd[i][1];
            float si = acc[i][2] + hadd[i][2];
            float sg = acc[i][3] + hadd[i][3];
            float go = sigm_fast(so);
            float gf = sigm_fast(sf);
            float gi = sigm_fast(si);
            float gg = sigm_fast(sg);
            float cc = gf * cstate[i] + gi * gg;
            cstate[i] = cc;
            hnew[w * 20 + lf] = (bf16)(go * tanh_fast(cc));
        }
        __syncthreads();   // S1: hnew complete across threads

        // ---- publish own 16f slice of h(y) -> hg[y%3][b] (IC stores) ----
        if (tid < 256) {
            bf16* dst = hg + ((size_t)(y % 3) * 16 + b) * (66 * 192);
            int w = tid >> 2, fo = (tid & 3) * 4;
            u64 v = *(const u64*)(&hnew[w * 20 + fo]);
            ic_store64((u64*)(dst + (size_t)(w + 1) * 192 + 16 * j + fo), v);
        }
        __syncthreads();   // S2: vmcnt(0) drain => ALL publishes visible at IC
        // single-writer flag store (no RMW, no serialization)
        if (tid == 0) ic_store32(&myflags[j], (unsigned)(y + 1));

        // ---- prefetch Hbuf gate biases for row y+1 (spin shadow) ----
        if (y < 63) {
            const size_t prow = pbase + (size_t)(y + 1) * WW;
            #pragma unroll
            for (int i = 0; i < 2; ++i) {
                int w = (wn * 2 + i) * 16 + col;
                for (int r = 0; r < 4; ++r)
                    hadd[i][r] = (float)Hbuf[(size_t)(r * FEAT + fmine) * NP + prow + w];
            }
        }

        // ---- skip GEMM + residual out for row y-1 (spin shadow) ----
        if (y > 0) {
            const int ym = y - 1;
            f32x4 acc2 = {};
            int wsk = ntk * 16 + col;
            for (int kc = 0; kc < 6; ++kc) {
                bf16x8 bfr = *(const bf16x8*)(&hlds[(wsk + 1) * 200 + kc * 32 + quad * 8]);
                acc2 = __builtin_amdgcn_mfma_f32_16x16x32_bf16(Ak[kc], bfr, acc2, 0, 0, 0);
            }
            for (int r = 0; r < 4; ++r) {
                int co = 32 * j + mtk * 16 + quad * 4 + r;
                size_t xi = ((size_t)(b * CINCH + co) * HH + ym) * WW + wsk;
                out[xi] = x[xi] + b_skip[co] + acc2[r];
            }
        }
        __syncthreads();   // S3: hlds reads (gates+skip) done before restage

        // ---- spin: all 12 flags >= y+1 (parallel loads, ballot check) ----
        {
            const unsigned tgt = (unsigned)(y + 1);
            while (true) {
                unsigned v = (lane < 12) ? ic_load32(&myflags[lane]) : tgt;
                if (__ballot(v >= tgt) == ~0ull) break;
                __builtin_amdgcn_s_sleep(1);
            }
            asm volatile("" ::: "memory");   // keep stage loads after the poll
        }

        // ---- stage h(y) -> hlds (IC loads, 8B units, 512-wide) ----
        {
            const u64* src = (const u64*)(hg + ((size_t)(y % 3) * 16 + b) * (66 * 192));
            #pragma unroll
            for (int it = 0; it < 7; ++it) {
                int c = it * SCANT + tid;
                if (c < 66 * 48) {
                    u64 v = ic_load64(src + c);
                    int w = c / 48, fc = c % 48;
                    *(u64*)(&hlds[w * 200 + fc * 4]) = v;
                }
            }
        }
        __syncthreads();   // S4: stage visible to all
    }

    // ---- epilogue: skip GEMM + residual for row 63 (hlds = h(63)) ----
    {
        f32x4 acc2 = {};
        int wsk = ntk * 16 + col;
        for (int kc = 0; kc < 6; ++kc) {
            bf16x8 bfr = *(const bf16x8*)(&hlds[(wsk + 1) * 200 + kc * 32 + quad * 8]);
            acc2 = __builtin_amdgcn_mfma_f32_16x16x32_bf16(Ak[kc], bfr, acc2, 0, 0, 0);
        }
        for (int r = 0; r < 4; ++r) {
            int co = 32 * j + mtk * 16 + quad * 4 + r;
            size_t xi = ((size_t)(b * CINCH + co) * HH + 63) * WW + wsk;
            out[xi] = x[xi] + b_skip[co] + acc2[r];
        }
    }
}

// ============================================================
extern "C" void kernel_launch(void* const* d_in, const int* in_sizes, int n_in,
                              void* d_out, int out_size, void* d_ws, size_t ws_size,
                              hipStream_t stream) {
    const float* x      = (const float*)d_in[0];
    const float* w_i2s  = (const float*)d_in[1];
    const float* w_s2s  = (const float*)d_in[2];
    const float* w_skip = (const float*)d_in[3];
    const float* b_skip = (const float*)d_in[4];
    float* out = (float*)d_out;

    char* ws = (char*)d_ws;
    const size_t HBUF_B = (size_t)CGATE * NP * 2;        // 100,663,296
    bf16* Hbuf = (bf16*)ws;
    size_t off = HBUF_B;
    bf16* WpA  = (bf16*)(ws + off); off += (size_t)CGATE * KI2S * 2;
    bf16* WpS  = (bf16*)(ws + off); off += (size_t)CGATE * KS2S * 2;
    bf16* WpK  = (bf16*)(ws + off); off += (size_t)CINCH * FEAT * 2;
    bf16* hg   = (bf16*)(ws + off); off += (size_t)3 * 16 * 66 * 192 * 2;
    unsigned* cnt = (unsigned*)(ws + off);               // 16*32 u32 = 2 KB
    bf16* Xp   = (bf16*)d_out;   // im2col scratch in d_out; dead before scan writes out

    pack_weights<<<256, 256, 0, stream>>>(w_i2s, w_s2s, w_skip, WpA, WpS, WpK);
    pack_x<<<BATCH * HH, 256, 0, stream>>>(x, Xp);
    dim3 g3(NP / 128, CGATE / 128);
    gemm_i2s<<<g3, 256, 0, stream>>>(WpA, Xp, Hbuf);

    void* args[] = { (void*)&Hbuf, (void*)&WpS, (void*)&WpK,
                     (void*)&x, (void*)&b_skip, (void*)&out, (void*)&hg, (void*)&cnt };
    hipLaunchCooperativeKernel((const void*)scan_kernel, dim3(NBLK), dim3(SCANT),
                               args, 0, stream);
}